// Round 1
// baseline (82.281 us; speedup 1.0000x reference)
//
#include <hip/hip_runtime.h>

// Problem constants (from reference): B=64, S=32768, R=4, W=4.
// out[b,s,r] = | prod_w cos(0.5*(x[b,s,w] - refs[r,w])) |
// x: (B,S,W) f32 contiguous, refs: (R,W) f32, out: (B,S,R) f32.
// Memory-bound: 33.5 MB in + 33.5 MB out => ~10.6 us at 6.3 TB/s.

#define QKE_R 4
#define QKE_W 4

__global__ __launch_bounds__(256) void
QuantumKernelEmbedding_kernel(const float* __restrict__ x,
                              const float* __restrict__ refs,
                              float* __restrict__ out,
                              int npts) {
    // Half-scaled refs in registers (uniform across wave; L1-broadcast reads).
    float rf[QKE_R][QKE_W];
#pragma unroll
    for (int r = 0; r < QKE_R; ++r)
#pragma unroll
        for (int w = 0; w < QKE_W; ++w)
            rf[r][w] = 0.5f * refs[r * QKE_W + w];

    const float4* __restrict__ x4 = reinterpret_cast<const float4*>(x);
    float4* __restrict__ o4 = reinterpret_cast<float4*>(out);

    int idx = blockIdx.x * blockDim.x + threadIdx.x;
    int stride = gridDim.x * blockDim.x;

    for (int i = idx; i < npts; i += stride) {
        float4 xv = x4[i];  // 16B coalesced load: the 4 wires of point i
        float hx[QKE_W] = {0.5f * xv.x, 0.5f * xv.y, 0.5f * xv.z, 0.5f * xv.w};

        float res[QKE_R];
#pragma unroll
        for (int r = 0; r < QKE_R; ++r) {
            float p = 1.0f;
#pragma unroll
            for (int w = 0; w < QKE_W; ++w)
                p *= __cosf(hx[w] - rf[r][w]);
            res[r] = fabsf(p);
        }
        // r is the innermost output dim -> 16B coalesced store
        o4[i] = make_float4(res[0], res[1], res[2], res[3]);
    }
}

extern "C" void kernel_launch(void* const* d_in, const int* in_sizes, int n_in,
                              void* d_out, int out_size, void* d_ws, size_t ws_size,
                              hipStream_t stream) {
    const float* x = (const float*)d_in[0];     // (B,S,W) f32
    const float* refs = (const float*)d_in[1];  // (R,W) f32
    float* out = (float*)d_out;                 // (B,S,R) f32

    const int npts = in_sizes[0] / QKE_W;  // B*S = 2,097,152

    const int block = 256;
    // Memory-bound: cap grid, grid-stride the rest (4 pts/thread at 2048 blocks).
    int grid = (npts + block - 1) / block;
    if (grid > 2048) grid = 2048;

    QuantumKernelEmbedding_kernel<<<grid, block, 0, stream>>>(x, refs, out, npts);
}